// Round 1
// baseline (161.164 us; speedup 1.0000x reference)
//
#include <hip/hip_runtime.h>
#include <math.h>

#define NN 256
#define TT 256
#define DD 1024
#define HH 1024

// ---------------------------------------------------------------------------
// Kernel 1: max-pool over token dim. grid (256, 2), block 256.
// Each block: one n of one tensor; thread d4 owns float4 column; loop t.
// Coalesced: 64 lanes x 16B = 1KB/instr. 4 independent accumulators for ILP.
// ---------------------------------------------------------------------------
__global__ __launch_bounds__(256) void pool_kernel(const float* __restrict__ subs,
                                                   const float* __restrict__ objs,
                                                   float* __restrict__ pooled) {
    const int n = blockIdx.x;
    const int which = blockIdx.y;
    const float* src = (which == 0) ? subs : objs;
    const int d4 = threadIdx.x; // float4 index, 0..255
    const float4* base = reinterpret_cast<const float4*>(src + (size_t)n * TT * DD) + d4;

    float4 a0 = make_float4(-INFINITY, -INFINITY, -INFINITY, -INFINITY);
    float4 a1 = a0, a2 = a0, a3 = a0;
    for (int t = 0; t < TT; t += 4) {
        float4 v0 = base[(size_t)(t + 0) * (DD / 4)];
        float4 v1 = base[(size_t)(t + 1) * (DD / 4)];
        float4 v2 = base[(size_t)(t + 2) * (DD / 4)];
        float4 v3 = base[(size_t)(t + 3) * (DD / 4)];
        a0.x = fmaxf(a0.x, v0.x); a0.y = fmaxf(a0.y, v0.y); a0.z = fmaxf(a0.z, v0.z); a0.w = fmaxf(a0.w, v0.w);
        a1.x = fmaxf(a1.x, v1.x); a1.y = fmaxf(a1.y, v1.y); a1.z = fmaxf(a1.z, v1.z); a1.w = fmaxf(a1.w, v1.w);
        a2.x = fmaxf(a2.x, v2.x); a2.y = fmaxf(a2.y, v2.y); a2.z = fmaxf(a2.z, v2.z); a2.w = fmaxf(a2.w, v2.w);
        a3.x = fmaxf(a3.x, v3.x); a3.y = fmaxf(a3.y, v3.y); a3.z = fmaxf(a3.z, v3.z); a3.w = fmaxf(a3.w, v3.w);
    }
    float4 m;
    m.x = fmaxf(fmaxf(a0.x, a1.x), fmaxf(a2.x, a3.x));
    m.y = fmaxf(fmaxf(a0.y, a1.y), fmaxf(a2.y, a3.y));
    m.z = fmaxf(fmaxf(a0.z, a1.z), fmaxf(a2.z, a3.z));
    m.w = fmaxf(fmaxf(a0.w, a1.w), fmaxf(a2.w, a3.w));
    float4* dst = reinterpret_cast<float4*>(pooled + (size_t)(which * NN + n) * DD) + d4;
    *dst = m;
}

// ---------------------------------------------------------------------------
// Kernel 2: fp32 GEMM  out[m][h] = sum_d A[m][d] * W1[h][koff+d]  (+b1 if sub)
// A = stacked pooled [512][1024]; rows <256 use W1[:, :1024], >=256 use W1[:,1024:].
// BM=32, BN=64, BK=32; 256 threads (16x16); micro-tile 2(m) x 4(n).
// LDS tiles stored k-outer so inner reads are b64/b128, conflict-free.
// Register prefetch of next K-chunk hides global latency (1 block/CU).
// ---------------------------------------------------------------------------
#define BM 32
#define BN 64
#define BK 32

__global__ __launch_bounds__(256) void gemm_kernel(const float* __restrict__ A,
                                                   const float* __restrict__ W1,
                                                   const float* __restrict__ b1,
                                                   float* __restrict__ out) {
    __shared__ float As[BK][BM];
    __shared__ float Bs[BK][BN];
    const int t = threadIdx.x;
    const int tx = t & 15, ty = t >> 4;
    const int m0 = blockIdx.y * BM;
    const int n0 = blockIdx.x * BN;
    const bool is_sub = (m0 < NN);
    const int koff = is_sub ? 0 : DD;

    // staging geometry
    const int a_m = t >> 3;            // 0..31
    const int a_k = (t & 7) * 4;       // 0,4,..,28
    const int b_n = t >> 3;            // 0..31 (round 0); +32 in round 1
    const int b_k = (t & 7) * 4;

    const float* Aptr  = A  + (size_t)(m0 + a_m) * DD + a_k;
    const float* Bptr0 = W1 + (size_t)(n0 + b_n) * (2 * DD) + koff + b_k;
    const float* Bptr1 = W1 + (size_t)(n0 + 32 + b_n) * (2 * DD) + koff + b_k;

    float acc[2][4] = {{0.f, 0.f, 0.f, 0.f}, {0.f, 0.f, 0.f, 0.f}};

    // prologue: chunk 0
    float4 pa  = *(const float4*)(Aptr);
    float4 pb0 = *(const float4*)(Bptr0);
    float4 pb1 = *(const float4*)(Bptr1);
    As[a_k + 0][a_m] = pa.x;  As[a_k + 1][a_m] = pa.y;  As[a_k + 2][a_m] = pa.z;  As[a_k + 3][a_m] = pa.w;
    Bs[b_k + 0][b_n] = pb0.x; Bs[b_k + 1][b_n] = pb0.y; Bs[b_k + 2][b_n] = pb0.z; Bs[b_k + 3][b_n] = pb0.w;
    Bs[b_k + 0][b_n + 32] = pb1.x; Bs[b_k + 1][b_n + 32] = pb1.y;
    Bs[b_k + 2][b_n + 32] = pb1.z; Bs[b_k + 3][b_n + 32] = pb1.w;
    __syncthreads();

    const int NCHUNK = DD / BK; // 32
    for (int c = 0; c < NCHUNK; ++c) {
        float4 na, nb0, nb1;
        if (c + 1 < NCHUNK) {
            const int off = (c + 1) * BK;
            na  = *(const float4*)(Aptr + off);
            nb0 = *(const float4*)(Bptr0 + off);
            nb1 = *(const float4*)(Bptr1 + off);
        }
#pragma unroll
        for (int k = 0; k < BK; ++k) {
            float2 a = *(const float2*)&As[k][ty * 2];
            float4 b = *(const float4*)&Bs[k][tx * 4];
            acc[0][0] += a.x * b.x; acc[0][1] += a.x * b.y;
            acc[0][2] += a.x * b.z; acc[0][3] += a.x * b.w;
            acc[1][0] += a.y * b.x; acc[1][1] += a.y * b.y;
            acc[1][2] += a.y * b.z; acc[1][3] += a.y * b.w;
        }
        __syncthreads();
        if (c + 1 < NCHUNK) {
            As[a_k + 0][a_m] = na.x;  As[a_k + 1][a_m] = na.y;
            As[a_k + 2][a_m] = na.z;  As[a_k + 3][a_m] = na.w;
            Bs[b_k + 0][b_n] = nb0.x; Bs[b_k + 1][b_n] = nb0.y;
            Bs[b_k + 2][b_n] = nb0.z; Bs[b_k + 3][b_n] = nb0.w;
            Bs[b_k + 0][b_n + 32] = nb1.x; Bs[b_k + 1][b_n + 32] = nb1.y;
            Bs[b_k + 2][b_n + 32] = nb1.z; Bs[b_k + 3][b_n + 32] = nb1.w;
            __syncthreads();
        }
    }

    // epilogue: fold b1 into subject half
    float4 bias = make_float4(0.f, 0.f, 0.f, 0.f);
    if (is_sub) bias = *(const float4*)&b1[n0 + tx * 4];
#pragma unroll
    for (int mi = 0; mi < 2; ++mi) {
        const int mg = m0 + ty * 2 + mi;
        float4 r;
        r.x = acc[mi][0] + bias.x; r.y = acc[mi][1] + bias.y;
        r.z = acc[mi][2] + bias.z; r.w = acc[mi][3] + bias.w;
        *(float4*)&out[(size_t)mg * HH + n0 + tx * 4] = r;
    }
}

// ---------------------------------------------------------------------------
// Kernel 3: pair scores.  scores[i,j] = sum_h relu(sp[i,h]+op[j,h]) * w2[h] + b2
// grid (16,16) -> 16x16 pair tile per block, 256 threads, 1 pair/thread.
// sp/op tiles staged in LDS, rows padded +4 floats (kills 16-way bank conflict
// on the tx-indexed reads: bank = (tx*132+4h)%32 spreads over banks).
// ---------------------------------------------------------------------------
#define HC 128

__global__ __launch_bounds__(256) void pair_kernel(const float* __restrict__ sp_op,
                                                   const float* __restrict__ W2,
                                                   const float* __restrict__ b2,
                                                   float* __restrict__ out) {
    __shared__ float sT[16][HC + 4];
    __shared__ float oT[16][HC + 4];
    __shared__ float w2s[HH];
    const int t = threadIdx.x;
    const int tx = t & 15, ty = t >> 4;
    const int i0 = blockIdx.y * 16, j0 = blockIdx.x * 16;
    const float* sp = sp_op;                       // rows 0..255 (b1 folded)
    const float* op = sp_op + (size_t)NN * HH;     // rows 256..511

    // stage w2 once (covered by first __syncthreads below)
    *(float4*)&w2s[t * 4] = *(const float4*)&W2[t * 4];

    const int s_row = t >> 5;        // 0..7 (round r adds 8)
    const int s_h = (t & 31) * 4;    // 0..124

    float acc = 0.f;
    for (int c = 0; c < HH / HC; ++c) {
        __syncthreads();
#pragma unroll
        for (int r = 0; r < 2; ++r) {
            const int row = s_row + r * 8;
            *(float4*)&sT[row][s_h] = *(const float4*)&sp[(size_t)(i0 + row) * HH + c * HC + s_h];
            *(float4*)&oT[row][s_h] = *(const float4*)&op[(size_t)(j0 + row) * HH + c * HC + s_h];
        }
        __syncthreads();
#pragma unroll
        for (int h4 = 0; h4 < HC / 4; ++h4) {
            float4 s = *(const float4*)&sT[ty][h4 * 4];
            float4 o = *(const float4*)&oT[tx][h4 * 4];
            float4 w = *(const float4*)&w2s[c * HC + h4 * 4];
            acc += fmaxf(s.x + o.x, 0.f) * w.x;
            acc += fmaxf(s.y + o.y, 0.f) * w.y;
            acc += fmaxf(s.z + o.z, 0.f) * w.z;
            acc += fmaxf(s.w + o.w, 0.f) * w.w;
        }
    }
    const int i = i0 + ty, j = j0 + tx;
    const float score = acc + b2[0];
    out[i * NN + j] = (i == j) ? 0.f : score;
}

// ---------------------------------------------------------------------------
extern "C" void kernel_launch(void* const* d_in, const int* in_sizes, int n_in,
                              void* d_out, int out_size, void* d_ws, size_t ws_size,
                              hipStream_t stream) {
    const float* subs = (const float*)d_in[0];
    const float* objs = (const float*)d_in[1];
    const float* W1   = (const float*)d_in[2];
    const float* b1   = (const float*)d_in[3];
    const float* W2   = (const float*)d_in[4];
    const float* b2   = (const float*)d_in[5];
    float* out = (float*)d_out;

    float* pooled = (float*)d_ws;                        // [512][1024]
    float* sp_op  = pooled + (size_t)2 * NN * DD;        // [512][1024]

    pool_kernel<<<dim3(NN, 2), 256, 0, stream>>>(subs, objs, pooled);
    gemm_kernel<<<dim3(HH / BN, (2 * NN) / BM), 256, 0, stream>>>(pooled, W1, b1, sp_op);
    pair_kernel<<<dim3(NN / 16, NN / 16), 256, 0, stream>>>(sp_op, W2, b2, out);
}